// Round 5
// baseline (427.264 us; speedup 1.0000x reference)
//
#include <hip/hip_runtime.h>

// Problem dims (fixed by setup_inputs)
#define D_   160
#define H_   192
#define W_   160
#define W4_  40              // W_/4
#define HW_  (H_*W_)         // 30720
#define HW4_ (HW_/4)         // 7680
#define N_   (D_*HW_)        // 4915200
#define NF4_ (N_/4)          // 1228800

#define SD    5              // D-outputs per thread
#define HP_   96             // h-pairs (H_/2)
#define NSEGD (D_/SD)        // 32
#define LNCC_BLOCKS 480      // 40*96*32/256
#define GRAD_BLOCKS 2880
#define GITER 5              // 2880*256*5 = 3686400 = 3*NF4_

// ---------------------------------------------------------------- reductions
__device__ __forceinline__ float blockReduceSum(float v) {
    __shared__ float red_s[16];
    const int lane = threadIdx.x & 63;
    const int wid  = threadIdx.x >> 6;
    #pragma unroll
    for (int off = 32; off > 0; off >>= 1) v += __shfl_down(v, off, 64);
    __syncthreads();
    if (lane == 0) red_s[wid] = v;
    __syncthreads();
    const int nw = (blockDim.x + 63) >> 6;
    v = (threadIdx.x < nw) ? red_s[threadIdx.x] : 0.0f;
    if (wid == 0) {
        #pragma unroll
        for (int off = 8; off > 0; off >>= 1) v += __shfl_down(v, off, 64);
    }
    return v;  // valid on thread 0
}

// 9-tap sums for 4 consecutive outputs from a 12-element window.
__device__ __forceinline__ float4 win9(const float e[12]) {
    float a = ((e[0]+e[1])+(e[2]+e[3]))+((e[4]+e[5])+(e[6]+e[7]))+e[8];
    float b = a + e[9]  - e[0];
    float c = b + e[10] - e[1];
    float d = c + e[11] - e[2];
    return make_float4(a, b, c, d);
}

// W-window sums of the 5 fields for one input row (4 outputs per thread).
__device__ __forceinline__ void rowSums(const float4* __restrict__ I4,
                                        const float4* __restrict__ J4,
                                        int rb4, int w4,
                                        float4& rI, float4& rJ,
                                        float4& rII, float4& rJJ, float4& rIJ) {
    const float4 z = make_float4(0.f, 0.f, 0.f, 0.f);
    float4 iL = (w4 > 0)       ? I4[rb4 + w4 - 1] : z;
    float4 iC =                  I4[rb4 + w4];
    float4 iR = (w4 < W4_ - 1) ? I4[rb4 + w4 + 1] : z;
    float4 jL = (w4 > 0)       ? J4[rb4 + w4 - 1] : z;
    float4 jC =                  J4[rb4 + w4];
    float4 jR = (w4 < W4_ - 1) ? J4[rb4 + w4 + 1] : z;

    float eI[12] = {iL.x,iL.y,iL.z,iL.w, iC.x,iC.y,iC.z,iC.w, iR.x,iR.y,iR.z,iR.w};
    float eJ[12] = {jL.x,jL.y,jL.z,jL.w, jC.x,jC.y,jC.z,jC.w, jR.x,jR.y,jR.z,jR.w};
    float eII[12], eJJ[12], eIJ[12];
    #pragma unroll
    for (int k = 0; k < 12; ++k) {
        eII[k] = eI[k] * eI[k];
        eJJ[k] = eJ[k] * eJ[k];
        eIJ[k] = eI[k] * eJ[k];
    }
    rI  = win9(eI);
    rJ  = win9(eJ);
    rII = win9(eII);
    rJJ = win9(eJJ);
    rIJ = win9(eIJ);
}

// --------------------------------------------------------- per-voxel cc value
__device__ __forceinline__ float ccf(float sI, float sJ, float sII,
                                     float sJJ, float sIJ) {
    const float inv = 1.0f / 729.0f;
    float cross = sIJ - sI * sJ * inv;
    float Iv    = sII - sI * sI * inv;
    float Jv    = sJJ - sJ * sJ * inv;
    return cross * cross / (Iv * Jv + 1e-5f);
}

// ------------------------------------------------- fused LNCC + gradient kernel
__global__ void __launch_bounds__(256)
fusedK(const float* __restrict__ I, const float* __restrict__ J,
       const float* __restrict__ dsp, float* __restrict__ parts) {
    if (blockIdx.x < LNCC_BLOCKS) {
        // ---------------- LNCC role: thread owns rows (h, h+1) at (w4), marches d
        const float4* I4 = (const float4*)I;
        const float4* J4 = (const float4*)J;
        int gtid = blockIdx.x * 256 + threadIdx.x;    // 122880 total
        int w4   = gtid % W4_;
        int t    = gtid / W4_;
        int hp   = t % HP_;
        int dseg = t / HP_;                            // 0..31
        int h    = hp * 2;
        int d0   = dseg * SD;

        float4 sA[5], sB[5];
        #pragma unroll
        for (int f = 0; f < 5; ++f) {
            sA[f] = make_float4(0,0,0,0);
            sB[f] = make_float4(0,0,0,0);
        }

        // accumulate one WH slab at depth z with sign into sA (rows h-4..h+4)
        // and sB (rows h-3..h+5)
        auto slab = [&](int z, float sign) {
            if (z < 0 || z >= D_) return;
            int zb4 = z * HW4_;
            float4 A[5], B[5];
            #pragma unroll
            for (int f = 0; f < 5; ++f) {
                A[f] = make_float4(0,0,0,0);
                B[f] = make_float4(0,0,0,0);
            }
            #pragma unroll 2
            for (int r = h - 4; r <= h + 5; ++r) {
                if (r < 0 || r >= H_) continue;
                float4 v[5];
                rowSums(I4, J4, zb4 + r * W4_, w4, v[0], v[1], v[2], v[3], v[4]);
                if (r <= h + 4) {
                    #pragma unroll
                    for (int f = 0; f < 5; ++f) {
                        A[f].x += v[f].x; A[f].y += v[f].y;
                        A[f].z += v[f].z; A[f].w += v[f].w;
                    }
                }
                if (r >= h - 3) {
                    #pragma unroll
                    for (int f = 0; f < 5; ++f) {
                        B[f].x += v[f].x; B[f].y += v[f].y;
                        B[f].z += v[f].z; B[f].w += v[f].w;
                    }
                }
            }
            #pragma unroll
            for (int f = 0; f < 5; ++f) {
                sA[f].x += sign * A[f].x; sA[f].y += sign * A[f].y;
                sA[f].z += sign * A[f].z; sA[f].w += sign * A[f].w;
                sB[f].x += sign * B[f].x; sB[f].y += sign * B[f].y;
                sB[f].z += sign * B[f].z; sB[f].w += sign * B[f].w;
            }
        };

        // prime the D-window: z in [d0-4, d0+4]
        #pragma unroll 1
        for (int z = d0 - 4; z <= d0 + 4; ++z) slab(z, 1.0f);

        float acc = 0.0f;
        #pragma unroll 1
        for (int dd = 0; dd < SD; ++dd) {
            acc += ccf(sA[0].x, sA[1].x, sA[2].x, sA[3].x, sA[4].x);
            acc += ccf(sA[0].y, sA[1].y, sA[2].y, sA[3].y, sA[4].y);
            acc += ccf(sA[0].z, sA[1].z, sA[2].z, sA[3].z, sA[4].z);
            acc += ccf(sA[0].w, sA[1].w, sA[2].w, sA[3].w, sA[4].w);
            acc += ccf(sB[0].x, sB[1].x, sB[2].x, sB[3].x, sB[4].x);
            acc += ccf(sB[0].y, sB[1].y, sB[2].y, sB[3].y, sB[4].y);
            acc += ccf(sB[0].z, sB[1].z, sB[2].z, sB[3].z, sB[4].z);
            acc += ccf(sB[0].w, sB[1].w, sB[2].w, sB[3].w, sB[4].w);
            if (dd < SD - 1) {
                int d = d0 + dd;
                slab(d + 5,  1.0f);
                slab(d - 4, -1.0f);
            }
        }

        float tot = blockReduceSum(acc);
        if (threadIdx.x == 0) parts[blockIdx.x] = tot;
    } else {
        // ---------------- gradient role (pre-normalized per-axis partials)
        const float4* s4 = (const float4*)dsp;
        const float invNx = 1.0f / (3.0f * D_ * (H_ - 1) * W_);   // h-diffs
        const float invNy = 1.0f / (3.0f * (D_ - 1) * H_ * W_);   // d-diffs
        const float invNz = 1.0f / (3.0f * D_ * H_ * (W_ - 1));   // w-diffs

        int bid2 = blockIdx.x - LNCC_BLOCKS;
        float acc = 0.0f;
        int tid0 = bid2 * 256 + threadIdx.x;
        #pragma unroll 1
        for (int it = 0; it < GITER; ++it) {
            int f  = tid0 + it * (GRAD_BLOCKS * 256);
            int w4 = f % W4_;
            int t  = f / W4_;
            int hh = t % H_;
            int t2 = t / H_;
            int dz = t2 % D_;

            float4 A = s4[f];
            float wss, hss = 0.f, dss = 0.f;
            { float a = A.y - A.x, b = A.z - A.y, c = A.w - A.z;
              wss = a*a + b*b + c*c; }
            if (w4 < W4_ - 1) { float b = dsp[f*4 + 4]; float u = b - A.w; wss += u*u; }
            if (hh < H_ - 1) {
                float4 C = s4[f + W4_];
                float a = C.x-A.x, b = C.y-A.y, c = C.z-A.z, e = C.w-A.w;
                hss = a*a + b*b + c*c + e*e;
            }
            if (dz < D_ - 1) {
                float4 Dv = s4[f + HW4_];
                float a = Dv.x-A.x, b = Dv.y-A.y, c = Dv.z-A.z, e = Dv.w-A.w;
                dss = a*a + b*b + c*c + e*e;
            }
            acc += wss * invNz + hss * invNx + dss * invNy;
        }

        float tot = blockReduceSum(acc);
        if (threadIdx.x == 0) parts[blockIdx.x] = tot;
    }
}

// ------------------------------------------------------------- final combine
__global__ void __launch_bounds__(256)
finalK(const float* __restrict__ parts, float* __restrict__ out) {
    float a = 0.f;
    for (int i = threadIdx.x; i < LNCC_BLOCKS; i += 256) a += parts[i];
    float b = 0.f;
    for (int i = LNCC_BLOCKS + threadIdx.x; i < LNCC_BLOCKS + GRAD_BLOCKS; i += 256)
        b += parts[i];
    float ccs = blockReduceSum(a);
    float gds = blockReduceSum(b);
    if (threadIdx.x == 0) {
        out[0] = (1.0f - ccs / (float)N_) + 0.01f * gds / 3.0f;
    }
}

// ---------------------------------------------------------------------- launch
extern "C" void kernel_launch(void* const* d_in, const int* in_sizes, int n_in,
                              void* d_out, int out_size, void* d_ws, size_t ws_size,
                              hipStream_t stream) {
    const float* I   = (const float*)d_in[0];   // y_fwd  (N_)
    const float* J   = (const float*)d_in[1];   // y_inv  (N_)
    const float* dsp = (const float*)d_in[2];   // dsp_fields (3*N_)
    float* out = (float*)d_out;

    float* parts = (float*)d_ws;                 // LNCC_BLOCKS + GRAD_BLOCKS floats

    fusedK<<<LNCC_BLOCKS + GRAD_BLOCKS, 256, 0, stream>>>(I, J, dsp, parts);
    finalK<<<1, 256, 0, stream>>>(parts, out);
}

// Round 7
// 255.431 us; speedup vs baseline: 1.6727x; 1.6727x over previous
//
#include <hip/hip_runtime.h>

// Problem dims (fixed by setup_inputs)
#define D_   160
#define H_   192
#define W_   160
#define W4_  40              // W_/4
#define HW_  (H_*W_)         // 30720
#define HW4_ (HW_/4)         // 7680
#define N_   (D_*HW_)        // 4915200
#define NF4_ (N_/4)          // 1228800

// Launch A: pass1 (W+H box sums -> buf) + grad, block-role interleaved 5:9
#define SEGH        3
#define AB_BLOCKS   1600     // 40*160*(192/3) threads / 256
#define GRAD_BLOCKS 2880
#define GITER       5        // 2880*256*5 = 3686400 = 3*NF4_
#define A_BLOCKS    (AB_BLOCKS + GRAD_BLOCKS)   // 4480 = 320*14

// Launch B: D box-sum + cc + full reduction (last-block combine)
#define SEGD     4
#define C_BLOCKS 1200        // 40*192*(160/4) threads / 256

// ---------------------------------------------------------------- reductions
__device__ __forceinline__ float blockReduceSum(float v) {
    __shared__ float red_s[16];
    const int lane = threadIdx.x & 63;
    const int wid  = threadIdx.x >> 6;
    #pragma unroll
    for (int off = 32; off > 0; off >>= 1) v += __shfl_down(v, off, 64);
    __syncthreads();
    if (lane == 0) red_s[wid] = v;
    __syncthreads();
    const int nw = (blockDim.x + 63) >> 6;
    v = (threadIdx.x < nw) ? red_s[threadIdx.x] : 0.0f;
    if (wid == 0) {
        #pragma unroll
        for (int off = 8; off > 0; off >>= 1) v += __shfl_down(v, off, 64);
    }
    return v;  // valid on thread 0
}

// 9-tap sums for 4 consecutive outputs from a 12-element window.
__device__ __forceinline__ float4 win9(const float e[12]) {
    float a = ((e[0]+e[1])+(e[2]+e[3]))+((e[4]+e[5])+(e[6]+e[7]))+e[8];
    float b = a + e[9]  - e[0];
    float c = b + e[10] - e[1];
    float d = c + e[11] - e[2];
    return make_float4(a, b, c, d);
}

// W-window sums of the 5 fields for one input row (4 outputs per thread).
// Branch-free edges: clamped addresses + select-to-zero.
__device__ __forceinline__ void rowSums(const float4* __restrict__ I4,
                                        const float4* __restrict__ J4,
                                        int rb4, int w4, float4 v[5]) {
    const float4 z4 = make_float4(0.f, 0.f, 0.f, 0.f);
    int wm = (w4 > 0)        ? w4 - 1 : 0;
    int wp = (w4 < W4_ - 1)  ? w4 + 1 : w4;
    float4 iL = I4[rb4 + wm], iC = I4[rb4 + w4], iR = I4[rb4 + wp];
    float4 jL = J4[rb4 + wm], jC = J4[rb4 + w4], jR = J4[rb4 + wp];
    if (w4 == 0)       { iL = z4; jL = z4; }
    if (w4 == W4_ - 1) { iR = z4; jR = z4; }

    float eI[12] = {iL.x,iL.y,iL.z,iL.w, iC.x,iC.y,iC.z,iC.w, iR.x,iR.y,iR.z,iR.w};
    float eJ[12] = {jL.x,jL.y,jL.z,jL.w, jC.x,jC.y,jC.z,jC.w, jR.x,jR.y,jR.z,jR.w};
    float eII[12], eJJ[12], eIJ[12];
    #pragma unroll
    for (int k = 0; k < 12; ++k) {
        eII[k] = eI[k] * eI[k];
        eJJ[k] = eJ[k] * eJ[k];
        eIJ[k] = eI[k] * eJ[k];
    }
    v[0] = win9(eI);
    v[1] = win9(eJ);
    v[2] = win9(eII);
    v[3] = win9(eJJ);
    v[4] = win9(eIJ);
}

// --------------------------------------------------------- per-voxel cc value
__device__ __forceinline__ float ccf(float sI, float sJ, float sII,
                                     float sJJ, float sIJ) {
    const float inv = 1.0f / 729.0f;
    float cross = sIJ - sI * sJ * inv;
    float Iv    = sII - sI * sI * inv;
    float Jv    = sJJ - sJ * sJ * inv;
    return cross * cross / (Iv * Jv + 1e-5f);
}

// ---------------------- launch A: pass1 (WH box sums) + gradient, interleaved
__global__ void __launch_bounds__(256)
kernA(const float* __restrict__ I, const float* __restrict__ J,
      const float* __restrict__ dsp, float* __restrict__ buf,
      float* __restrict__ accum) {
    int q = blockIdx.x / 14, rr = blockIdx.x % 14;
    if (rr < 5) {
        // ---------------- pass1 role: W+H box sums of 5 fields -> buf (SoA)
        int bid = q * 5 + rr;                      // 0..1599
        const float4* I4 = (const float4*)I;
        const float4* J4 = (const float4*)J;
        float4* out4 = (float4*)buf;

        int gtid = bid * 256 + threadIdx.x;        // 409600 total
        int w4   = gtid % W4_;
        int t    = gtid / W4_;
        int d    = t % D_;
        int hseg = t / D_;                          // 0..63
        int h0   = hseg * SEGH;
        int db4  = d * HW4_;

        float4 s[5];
        #pragma unroll
        for (int f = 0; f < 5; ++f) s[f] = make_float4(0,0,0,0);

        // prime rows h0-4 .. h0+4 (full unroll -> independent load batches)
        #pragma unroll
        for (int k = 0; k < 9; ++k) {
            int y = h0 - 4 + k;
            if (y >= 0 && y < H_) {
                float4 v[5];
                rowSums(I4, J4, db4 + y * W4_, w4, v);
                #pragma unroll
                for (int f = 0; f < 5; ++f) {
                    s[f].x += v[f].x; s[f].y += v[f].y;
                    s[f].z += v[f].z; s[f].w += v[f].w;
                }
            }
        }

        #pragma unroll
        for (int r = 0; r < SEGH; ++r) {
            int o4 = db4 + (h0 + r) * W4_ + w4;
            #pragma unroll
            for (int f = 0; f < 5; ++f) out4[f * NF4_ + o4] = s[f];
            if (r < SEGH - 1) {
                int ya = h0 + r + 5, yb = h0 + r - 4;
                if (ya < H_) {
                    float4 v[5];
                    rowSums(I4, J4, db4 + ya * W4_, w4, v);
                    #pragma unroll
                    for (int f = 0; f < 5; ++f) {
                        s[f].x += v[f].x; s[f].y += v[f].y;
                        s[f].z += v[f].z; s[f].w += v[f].w;
                    }
                }
                if (yb >= 0) {
                    float4 v[5];
                    rowSums(I4, J4, db4 + yb * W4_, w4, v);
                    #pragma unroll
                    for (int f = 0; f < 5; ++f) {
                        s[f].x -= v[f].x; s[f].y -= v[f].y;
                        s[f].z -= v[f].z; s[f].w -= v[f].w;
                    }
                }
            }
        }
    } else {
        // ---------------- gradient role (pre-normalized per-axis partials)
        int bid = q * 9 + (rr - 5);                // 0..2879
        const float4* s4 = (const float4*)dsp;
        const float invNx = 1.0f / (3.0f * D_ * (H_ - 1) * W_);   // h-diffs
        const float invNy = 1.0f / (3.0f * (D_ - 1) * H_ * W_);   // d-diffs
        const float invNz = 1.0f / (3.0f * D_ * H_ * (W_ - 1));   // w-diffs

        float acc = 0.0f;
        int tid0 = bid * 256 + threadIdx.x;
        #pragma unroll 1
        for (int it = 0; it < GITER; ++it) {
            int f  = tid0 + it * (GRAD_BLOCKS * 256);
            int w4 = f % W4_;
            int t  = f / W4_;
            int hh = t % H_;
            int t2 = t / H_;
            int dz = t2 % D_;

            float4 A = s4[f];
            float wss, hss = 0.f, dss = 0.f;
            { float a = A.y - A.x, b = A.z - A.y, c = A.w - A.z;
              wss = a*a + b*b + c*c; }
            if (w4 < W4_ - 1) { float b = dsp[f*4 + 4]; float u = b - A.w; wss += u*u; }
            if (hh < H_ - 1) {
                float4 C = s4[f + W4_];
                float a = C.x-A.x, b = C.y-A.y, c = C.z-A.z, e = C.w-A.w;
                hss = a*a + b*b + c*c + e*e;
            }
            if (dz < D_ - 1) {
                float4 Dv = s4[f + HW4_];
                float a = Dv.x-A.x, b = Dv.y-A.y, c = Dv.z-A.z, e = Dv.w-A.w;
                dss = a*a + b*b + c*c + e*e;
            }
            acc += wss * invNz + hss * invNx + dss * invNy;
        }

        float tot = blockReduceSum(acc);
        if (threadIdx.x == 0) atomicAdd(&accum[1], tot);
    }
}

// ------------- launch B: D box-sum + cc + reduction + last-block combine
__global__ void __launch_bounds__(256)
kernB(const float* __restrict__ buf, float* __restrict__ accum,
      int* __restrict__ counter, float* __restrict__ out) {
    const float4* in4 = (const float4*)buf;
    int gtid = blockIdx.x * 256 + threadIdx.x;   // 307200 total
    int w4   = gtid % W4_;
    int t    = gtid / W4_;
    int h    = t % H_;
    int dseg = t / H_;                            // 0..39
    int d0   = dseg * SEGD;
    int base4 = h * W4_ + w4;

    float4 s0 = make_float4(0,0,0,0), s1 = s0, s2 = s0, s3 = s0, s4v = s0;

    // prime z in [d0-4, d0+4] (full unroll; guards are block-uniform mostly)
    #pragma unroll
    for (int k = 0; k < 9; ++k) {
        int z = d0 - 4 + k;
        if (z >= 0 && z < D_) {
            int a4 = z * HW4_ + base4;
            float4 v0 = in4[0*NF4_ + a4], v1 = in4[1*NF4_ + a4];
            float4 v2 = in4[2*NF4_ + a4], v3 = in4[3*NF4_ + a4];
            float4 v4 = in4[4*NF4_ + a4];
            s0.x+=v0.x; s0.y+=v0.y; s0.z+=v0.z; s0.w+=v0.w;
            s1.x+=v1.x; s1.y+=v1.y; s1.z+=v1.z; s1.w+=v1.w;
            s2.x+=v2.x; s2.y+=v2.y; s2.z+=v2.z; s2.w+=v2.w;
            s3.x+=v3.x; s3.y+=v3.y; s3.z+=v3.z; s3.w+=v3.w;
            s4v.x+=v4.x; s4v.y+=v4.y; s4v.z+=v4.z; s4v.w+=v4.w;
        }
    }

    float acc = 0.0f;
    #pragma unroll
    for (int dd = 0; dd < SEGD; ++dd) {
        acc += ccf(s0.x, s1.x, s2.x, s3.x, s4v.x);
        acc += ccf(s0.y, s1.y, s2.y, s3.y, s4v.y);
        acc += ccf(s0.z, s1.z, s2.z, s3.z, s4v.z);
        acc += ccf(s0.w, s1.w, s2.w, s3.w, s4v.w);
        if (dd < SEGD - 1) {
            int d = d0 + dd;
            int za = d + 5, zb = d - 4;
            if (za < D_) {
                int a4 = za * HW4_ + base4;
                float4 v0 = in4[0*NF4_ + a4], v1 = in4[1*NF4_ + a4];
                float4 v2 = in4[2*NF4_ + a4], v3 = in4[3*NF4_ + a4];
                float4 v4 = in4[4*NF4_ + a4];
                s0.x+=v0.x; s0.y+=v0.y; s0.z+=v0.z; s0.w+=v0.w;
                s1.x+=v1.x; s1.y+=v1.y; s1.z+=v1.z; s1.w+=v1.w;
                s2.x+=v2.x; s2.y+=v2.y; s2.z+=v2.z; s2.w+=v2.w;
                s3.x+=v3.x; s3.y+=v3.y; s3.z+=v3.z; s3.w+=v3.w;
                s4v.x+=v4.x; s4v.y+=v4.y; s4v.z+=v4.z; s4v.w+=v4.w;
            }
            if (zb >= 0) {
                int a4 = zb * HW4_ + base4;
                float4 v0 = in4[0*NF4_ + a4], v1 = in4[1*NF4_ + a4];
                float4 v2 = in4[2*NF4_ + a4], v3 = in4[3*NF4_ + a4];
                float4 v4 = in4[4*NF4_ + a4];
                s0.x-=v0.x; s0.y-=v0.y; s0.z-=v0.z; s0.w-=v0.w;
                s1.x-=v1.x; s1.y-=v1.y; s1.z-=v1.z; s1.w-=v1.w;
                s2.x-=v2.x; s2.y-=v2.y; s2.z-=v2.z; s2.w-=v2.w;
                s3.x-=v3.x; s3.y-=v3.y; s3.z-=v3.z; s3.w-=v3.w;
                s4v.x-=v4.x; s4v.y-=v4.y; s4v.z-=v4.z; s4v.w-=v4.w;
            }
        }
    }

    float tot = blockReduceSum(acc);
    if (threadIdx.x == 0) {
        atomicAdd(&accum[0], tot);
        __threadfence();                              // order accum before counter
        int old = atomicAdd(counter, 1);
        if (old == C_BLOCKS - 1) {
            // last block: combine (atomic reads -> coherent point)
            float ccs = atomicAdd(&accum[0], 0.0f);
            float gds = atomicAdd(&accum[1], 0.0f);
            out[0] = (1.0f - ccs / (float)N_) + 0.01f * gds / 3.0f;
        }
    }
}

// ---------------------------------------------------------------------- launch
extern "C" void kernel_launch(void* const* d_in, const int* in_sizes, int n_in,
                              void* d_out, int out_size, void* d_ws, size_t ws_size,
                              hipStream_t stream) {
    const float* I   = (const float*)d_in[0];   // y_fwd  (N_)
    const float* J   = (const float*)d_in[1];   // y_inv  (N_)
    const float* dsp = (const float*)d_in[2];   // dsp_fields (3*N_)
    float* out = (float*)d_out;

    float* buf   = (float*)d_ws;                 // 5*N_ floats (~98.3 MB)
    float* accum = buf + (size_t)5 * N_;         // accum[0]=cc, accum[1]=grad
    int*   counter = (int*)(accum + 2);

    hipMemsetAsync(accum, 0, 4 * sizeof(float), stream);

    kernA<<<A_BLOCKS, 256, 0, stream>>>(I, J, dsp, buf, accum);
    kernB<<<C_BLOCKS, 256, 0, stream>>>(buf, accum, counter, out);
}